// Round 7
// baseline (356.328 us; speedup 1.0000x reference)
//
#include <hip/hip_runtime.h>
#include <hip/hip_bf16.h>

typedef __hip_bfloat16 bf16;
typedef __attribute__((ext_vector_type(8))) short bf16x8;
typedef __attribute__((ext_vector_type(4))) float f32x4;

#define BT     3200
#define N_     22
#define NO     1408           // N_*64
#define NN     484
#define BTN    70400
#define ELEMS  4505600        // BT*N_*64
#define MAXNZ  128
#define NSHARD 16
#define EPAD   96             // padded flattened edge count (real E = 84)
#define STATSZ (NSHARD * 384 + 8 * 128)

static __device__ __forceinline__ bf16  f2bf(float v) { return __float2bfloat16(v); }
static __device__ __forceinline__ short fbf(float v) {
    bf16 h = __float2bfloat16(v);
    return *reinterpret_cast<short*>(&h);
}
static __device__ __forceinline__ void unp(unsigned u, float& lo, float& hi) {
    lo = __uint_as_float(u << 16);
    hi = __uint_as_float(u & 0xffff0000u);
}

// ---------------------------------------------------------------------------
// Kernel 1 (prep): blocks 0-1 zero own AA plane + AA softmax; 2-7 CB; 8-17 WB;
// 18: stats zero + FLATTENED edge list (EPAD u16 entries (i<<5)|j; pad with
// (0,21), a non-edge in both planes -> AAb==0 -> adds exact 0) + attF.
// ---------------------------------------------------------------------------
__global__ void prep_kernel(const float* __restrict__ e_s, const int* __restrict__ rs,
                            const int* __restrict__ cs, int nnz_s,
                            const float* __restrict__ e_c, const int* __restrict__ rc,
                            const int* __restrict__ cc, int nnz_c,
                            const float* __restrict__ cat_w,
                            const float* __restrict__ Wsym, const float* __restrict__ Wcon,
                            const float* __restrict__ Wdis, const float* __restrict__ att,
                            short* __restrict__ AAb, short* __restrict__ CB,
                            short* __restrict__ WB, unsigned short* __restrict__ elist,
                            short* __restrict__ attF, float* __restrict__ stats) {
    const int tid = threadIdx.x;
    if (blockIdx.x < 2) {
        __shared__ float eL[64 * (MAXNZ + 1)];
        __shared__ int rowsL[MAXNZ], colsL[MAXNZ];
        const int t = blockIdx.x;
        const float* e    = t ? e_c : e_s;
        const int*   rows = t ? rc  : rs;
        const int*   cols = t ? cc  : cs;
        const int    nnz  = t ? nnz_c : nnz_s;
        const int    str  = nnz + 1;

        // zero this block's own interleaved plane (replaces hipMemsetAsync);
        // the __syncthreads below drains stores before the scatter writes.
        for (int idx = tid; idx < NN * 64; idx += 256) AAb[(size_t)idx * 2 + t] = 0;

        for (int idx = tid; idx < 64 * nnz; idx += 256) {
            int o = idx / nnz, k = idx - o * nnz;
            eL[o * str + k] = expf(e[idx]);
        }
        for (int idx = tid; idx < nnz; idx += 256) { rowsL[idx] = rows[idx]; colsL[idx] = cols[idx]; }
        __syncthreads();

        const int o = tid & 63, ig = tid >> 6;
        float s[6];
        #pragma unroll
        for (int q = 0; q < 6; q++) s[q] = 0.f;
        for (int k = 0; k < nnz; k++) {
            int r = rowsL[k];
            float ev = eL[o * str + k];
            #pragma unroll
            for (int q = 0; q < 6; q++)
                if (r == ig + 4 * q) s[q] += ev;
        }
        float inv[6];
        #pragma unroll
        for (int q = 0; q < 6; q++) inv[q] = 1.f / s[q];
        for (int k = 0; k < nnz; k++) {
            int r = rowsL[k];
            #pragma unroll
            for (int q = 0; q < 6; q++)
                if (r == ig + 4 * q)
                    AAb[((size_t)(r * N_ + colsL[k]) * 64 + o) * 2 + t] =
                        fbf(eL[o * str + k] * inv[q]);
        }
    } else if (blockIdx.x < 8) {
        int gi = (blockIdx.x - 2) * 256 + tid;
        if (gi >= 1536) return;
        int nt = gi / 384, rem = gi % 384;
        int kc = rem >> 6, L = rem & 63;
        int n = nt * 16 + (L & 15);
        int kbase = kc * 32 + (L >> 4) * 8;
        float4 w0 = *(const float4*)&cat_w[n * 192 + kbase];
        float4 w1 = *(const float4*)&cat_w[n * 192 + kbase + 4];
        bf16x8 frag;
        frag[0] = fbf(w0.x); frag[1] = fbf(w0.y); frag[2] = fbf(w0.z); frag[3] = fbf(w0.w);
        frag[4] = fbf(w1.x); frag[5] = fbf(w1.y); frag[6] = fbf(w1.z); frag[7] = fbf(w1.w);
        ((bf16x8*)CB)[gi] = frag;
    } else if (blockIdx.x < 18) {
        int gi = (blockIdx.x - 8) * 256 + tid;
        if (gi >= 2560) return;
        int L = gi & 63;
        int q = gi >> 6;
        int nt = q & 3;
        int pk = q >> 2;
        int kc = pk & 1;
        int p  = pk >> 1;
        const float* Wsrc = (p == 0) ? Wsym :
                            (p == 1) ? Wsym + 4096 :
                            (p == 2) ? Wcon :
                            (p == 3) ? Wcon + 4096 : Wdis;
        int n  = nt * 16 + (L & 15);
        int kb = kc * 32 + (L >> 4) * 8;
        bf16x8 frag;
        #pragma unroll
        for (int j = 0; j < 8; j++) frag[j] = fbf(Wsrc[(kb + j) * 64 + n]);
        ((bf16x8*)WB)[gi] = frag;
    } else {
        __shared__ unsigned bitsL[32];
        __shared__ int offL[32];
        // zero the atomic stats buffers (replaces hipMemsetAsync)
        for (int idx = tid; idx < STATSZ; idx += 256) stats[idx] = 0.f;
        // per-row off-diagonal union bitmaps
        if (tid < N_) {
            unsigned bits = 0u;
            for (int e = 0; e < nnz_s; e++)
                if (rs[e] == tid && cs[e] != tid) bits |= 1u << cs[e];
            for (int e = 0; e < nnz_c; e++)
                if (rc[e] == tid && cc[e] != tid) bits |= 1u << cc[e];
            bitsL[tid] = bits;
        }
        __syncthreads();
        if (tid == 0) {
            int off = 0;
            for (int i = 0; i < N_; i++) { offL[i] = off; off += __popc(bitsL[i]); }
            offL[N_] = off;
        }
        __syncthreads();
        if (tid < N_) {
            unsigned b = bitsL[tid];
            int o = offL[tid];
            while (b) {
                int j = __ffs(b) - 1; b &= b - 1;
                if (o < EPAD) elist[o] = (unsigned short)((tid << 5) | j);
                o++;
            }
        }
        int E = offL[N_] < EPAD ? offL[N_] : EPAD;
        for (int idx = E + tid; idx < EPAD; idx += 256)
            elist[idx] = (unsigned short)21;   // (0<<5)|21: zero in both planes
        // att A-fragments: A[m][k] = att[m][k] for m,k<22 else 0
        for (int f = tid; f < 128; f += 256) {
            int rt = f >> 6, LL = f & 63;
            int row = rt * 16 + (LL & 15);
            int kb  = (LL >> 4) * 8;
            bf16x8 frag;
            #pragma unroll
            for (int j = 0; j < 8; j++) {
                int k = kb + j;
                float vv = (row < N_ && k < N_) ? att[row * N_ + k] : 0.f;
                frag[j] = fbf(vv);
            }
            ((bf16x8*)attF)[f] = frag;
        }
    }
}

// ---------------------------------------------------------------------------
// Kernel 2: FUSED x-stage + h-GEMM + FLATTENED edge mixer + z-MFMA.
// 1 bt/block, grid 3200. Changes vs R3 (verified 172.6):
//  - h1s/h1c kept f32 (float2) in LDS: no bf16 pack/unpack on mixer path.
//  - diag term A[i,i]*h0 written as xacc/yacc INIT directly from MFMA regs.
//  - mixer: 24 fixed iterations over the 96-entry flattened edge list
//    (wave w takes entries e = t*4+w); LDS atomicAdd accumulation.
//    48 padded slots/thread -> 24 real units; 54 -> 32 global AAu loads.
// ---------------------------------------------------------------------------
__launch_bounds__(256)
__global__ void fused_hmix(const float* __restrict__ x, const short* __restrict__ WB,
                           const short* __restrict__ AAb, const short* __restrict__ attF,
                           const unsigned short* __restrict__ elist,
                           const float* __restrict__ bdis,
                           bf16* __restrict__ xs, bf16* __restrict__ yc,
                           bf16* __restrict__ z, float* __restrict__ stats1) {
    __shared__ __align__(16) char smem[25536];
    // phase A (staging) -- aliases the h12 region, dead before epilogue writes
    short*    xl   = (short*)smem;                  // [32][64] bf16, XOR-swizzled
    short*    dl   = (short*)(smem + 4096);
    float*    red4 = (float*)(smem + 8192);         // 512 f32
    // phase C (post-GEMM)
    float*    h12  = (float*)smem;                  // float2[22][64] {h1s,h1c}
    short*    p2   = (short*)(smem + 11264);        // bf16[22][64] hdw
    float*    xacc = (float*)(smem + 14080);        // f32[22][64]
    float*    yacc = (float*)(smem + 19712);        // f32[22][64]
    unsigned short* eL = (unsigned short*)(smem + 25344);  // 96 edge entries
    float*    red  = (float*)smem;                  // stats tail (aliases h12)

    const int g   = blockIdx.x;
    const int tid = threadIdx.x;
    const size_t base = (size_t)g * NO;
    const int w = tid >> 6, L = tid & 63;
    const int lane16 = L & 15, quad = L >> 4;
    const int colw = w * 16 + lane16;
    const bf16x8* WBf = (const bf16x8*)WB;
    const unsigned* AAu = (const unsigned*)AAb;

    // ---- (a) stage x + distance stats + edge-list stage
    if (tid < EPAD) eL[tid] = elist[tid];
    float v[6], s = 0.f, s2 = 0.f;
    #pragma unroll
    for (int k = 0; k < 6; k++) {
        int i = w + 4 * k;
        float t = (i < N_) ? x[base + i * 64 + L] : 0.f;
        v[k] = t; s += t; s2 += t * t;
    }
    red4[w * 64 + L]       = s;
    red4[256 + w * 64 + L] = s2;
    for (int idx = tid; idx < 320; idx += 256) {   // zero pad rows 22..31
        ((unsigned*)xl)[704 + idx] = 0u;
        ((unsigned*)dl)[704 + idx] = 0u;
    }
    __syncthreads();
    float S  = (red4[L] + red4[64 + L]) + (red4[128 + L] + red4[192 + L]);
    float S2 = (red4[256 + L] + red4[320 + L]) + (red4[384 + L] + red4[448 + L]);
    #pragma unroll
    for (int k = 0; k < 6; k++) {
        int i = w + 4 * k;
        if (i < N_) {
            float t = v[k];
            float d2 = S2 - 2.f * t * S + (float)N_ * t * t;
            float d  = sqrtf(fmaxf(d2, 0.f)) + 1e-8f;
            int ci = i * 64 + (L ^ ((i & 7) << 3));
            xl[ci] = fbf(t);
            dl[ci] = fbf(d);
        }
    }
    __syncthreads();

    // ---- (b) GEMM: 5 planes x 2 row-tiles x 2 k-chunks
    f32x4 acc[5][2];
    #pragma unroll
    for (int p = 0; p < 5; p++)
        #pragma unroll
        for (int rt = 0; rt < 2; rt++) acc[p][rt] = (f32x4){0.f, 0.f, 0.f, 0.f};

    #pragma unroll
    for (int kc = 0; kc < 2; kc++) {
        bf16x8 ax[2], ad[2];
        #pragma unroll
        for (int rt = 0; rt < 2; rt++) {
            int row = rt * 16 + lane16;
            int ci  = row * 64 + ((kc * 32 + quad * 8) ^ ((row & 7) << 3));
            ax[rt] = *(const bf16x8*)(xl + ci);
            ad[rt] = *(const bf16x8*)(dl + ci);
        }
        #pragma unroll
        for (int p = 0; p < 5; p++) {
            bf16x8 bw = WBf[((p * 2 + kc) * 4 + w) * 64 + L];
            #pragma unroll
            for (int rt = 0; rt < 2; rt++) {
                bf16x8 a = (p < 4) ? ax[rt] : ad[rt];
                acc[p][rt] = __builtin_amdgcn_mfma_f32_16x16x32_bf16(a, bw, acc[p][rt], 0, 0, 0);
            }
        }
    }
    __syncthreads();   // xl/dl reads done before h12 overwrite

    // ---- (c) epilogue: h1 (f32 pairs) + p2 + diag-initialized xacc/yacc
    unsigned adm[8];
    #pragma unroll
    for (int rt = 0; rt < 2; rt++)
        #pragma unroll
        for (int r = 0; r < 4; r++) {
            int m = rt * 16 + quad * 4 + r;
            adm[rt * 4 + r] = (m < N_) ? AAu[(size_t)(m * 23) * 64 + colw] : 0u;
        }
    #pragma unroll
    for (int rt = 0; rt < 2; rt++)
        #pragma unroll
        for (int r = 0; r < 4; r++) {
            int m = rt * 16 + quad * 4 + r;
            if (m < N_) {
                int ci = m * 64 + colw;
                *(float2*)&h12[ci * 2] = make_float2(acc[1][rt][r], acc[3][rt][r]);
                p2[ci] = fbf(acc[4][rt][r]);
                float asd, acd; unp(adm[rt * 4 + r], asd, acd);
                xacc[ci] = asd * acc[0][rt][r];   // diag term A[m,m]*h0s
                yacc[ci] = acd * acc[2][rt][r];   // diag term A[m,m]*h0c
            }
        }
    __syncthreads();

    // ---- (d) z = att @ hdw via MFMA (K=32 pad, rows >=22 masked to 0)
    f32x4 zacc[2];
    zacc[0] = (f32x4){0.f, 0.f, 0.f, 0.f};
    zacc[1] = (f32x4){0.f, 0.f, 0.f, 0.f};
    {
        bf16x8 bfrag;
        #pragma unroll
        for (int j = 0; j < 8; j++) {
            int k = quad * 8 + j;
            bfrag[j] = (k < N_) ? p2[k * 64 + colw] : (short)0;
        }
        const bf16x8* attFf = (const bf16x8*)attF;
        #pragma unroll
        for (int rt = 0; rt < 2; rt++)
            zacc[rt] = __builtin_amdgcn_mfma_f32_16x16x32_bf16(attFf[rt * 64 + L], bfrag,
                                                               zacc[rt], 0, 0, 0);
    }

    // ---- (e) flattened edge mixer: 24 fixed units/thread, LDS atomic accum
    #pragma unroll
    for (int t = 0; t < EPAD / 4; t++) {
        int ent = eL[t * 4 + w];                  // wave-uniform entry
        int i = ent >> 5, j = ent & 31;
        unsigned a = AAu[(size_t)(i * N_ + j) * 64 + L];
        float2 h = *(const float2*)&h12[(j * 64 + L) * 2];
        float as, ac; unp(a, as, ac);
        atomicAdd(&xacc[i * 64 + L], as * h.x);
        atomicAdd(&yacc[i * 64 + L], ac * h.y);
    }
    __syncthreads();   // all edge contributions + diag init landed

    // ---- outputs + stats: xs/yc (channel = L)
    float st0 = 0.f, st1 = 0.f, st2 = 0.f, st3 = 0.f;
    #pragma unroll
    for (int k = 0; k < 6; k++) {
        int i = w + 4 * k;
        if (i < N_) {
            float xsv = xacc[i * 64 + L];
            float ycv = yacc[i * 64 + L];
            size_t oi = base + i * 64 + L;
            xs[oi] = f2bf(xsv); yc[oi] = f2bf(ycv);
            st0 += xsv; st1 += xsv * xsv;
            st2 += ycv; st3 += ycv * ycv;
        }
    }

    // z outputs + stats (channel = colw)
    float bd = bdis[colw];
    float st4 = 0.f, st5 = 0.f;
    #pragma unroll
    for (int rt = 0; rt < 2; rt++)
        #pragma unroll
        for (int r = 0; r < 4; r++) {
            int m = rt * 16 + quad * 4 + r;
            if (m < N_) {
                float zv = zacc[rt][r] + bd;
                z[base + (size_t)m * 64 + colw] = f2bf(zv);
                st4 += zv; st5 += zv * zv;
            }
        }
    st4 += __shfl_xor(st4, 16); st4 += __shfl_xor(st4, 32);
    st5 += __shfl_xor(st5, 16); st5 += __shfl_xor(st5, 32);

    __syncthreads();               // xacc/yacc reads done; red aliases h12
    red[(w * 4 + 0) * 64 + L] = st0;
    red[(w * 4 + 1) * 64 + L] = st1;
    red[(w * 4 + 2) * 64 + L] = st2;
    red[(w * 4 + 3) * 64 + L] = st3;
    if (quad == 0) { red[16 * 64 + colw] = st4; red[17 * 64 + colw] = st5; }
    __syncthreads();
    float* myStats = stats1 + (size_t)(g & (NSHARD - 1)) * 384;
    for (int qq = tid; qq < 384; qq += 256) {
        int q = qq >> 6, o = qq & 63;
        float vv;
        if (q < 4)
            vv = (red[q * 64 + o] + red[(4 + q) * 64 + o]) +
                 (red[(8 + q) * 64 + o] + red[(12 + q) * 64 + o]);
        else
            vv = red[(12 + q) * 64 + o];   // q=4 -> row16, q=5 -> row17
        atomicAdd(&myStats[qq], vv);
    }
}

// ---------------------------------------------------------------------------
// Kernel 3: mix GEMM, 1100 blocks x 64 rows; scale1 computed in-block from
// stats1; stats2 sharded 8-way. (verified R3, unchanged)
// ---------------------------------------------------------------------------
__launch_bounds__(256)
__global__ void mix_pass(const bf16* __restrict__ xs, const bf16* __restrict__ yc,
                         const bf16* __restrict__ z, const float* __restrict__ stats1,
                         const float* __restrict__ gammas, const float* __restrict__ betas,
                         const short* __restrict__ CB,
                         bf16* __restrict__ out2, float* __restrict__ stats2) {
    __shared__ float sL[384];
    __shared__ float red[512];

    const int tid = threadIdx.x;
    const int w = tid >> 6, L = tid & 63;
    const int lane16 = L & 15, quad = L >> 4;
    const int R0 = blockIdx.x * 64 + w * 16;

    if (tid < 192) {
        int t = tid >> 6, o = tid & 63;
        float S = 0.f, SS = 0.f;
        for (int s = 0; s < NSHARD; s++) {
            S  += stats1[s * 384 + (2 * t) * 64 + o];
            SS += stats1[s * 384 + (2 * t + 1) * 64 + o];
        }
        const float invn = 1.f / (float)BTN;
        float mu   = S * invn;
        float var  = SS * invn - mu * mu;
        float rstd = rsqrtf(var + 1e-5f);
        float a = gammas[t * 64 + o] * rstd;
        float c = betas[t * 64 + o] - mu * a;
        sL[t * 128 + o]      = a;
        sL[t * 128 + 64 + o] = c;
    }
    __syncthreads();

    const bf16* srcs[3] = { xs, yc, z };

    f32x4 acc[4];
    #pragma unroll
    for (int nt = 0; nt < 4; nt++) acc[nt] = (f32x4){0.f, 0.f, 0.f, 0.f};

    #pragma unroll
    for (int kc = 0; kc < 6; kc++) {
        const int src = kc >> 1;
        const int c0  = (kc & 1) * 32 + quad * 8;
        int row = R0 + lane16;
        uint4 u = *(const uint4*)(srcs[src] + (size_t)row * 64 + c0);
        float v[8];
        unp(u.x, v[0], v[1]); unp(u.y, v[2], v[3]);
        unp(u.z, v[4], v[5]); unp(u.w, v[6], v[7]);
        bf16x8 av;
        #pragma unroll
        for (int e = 0; e < 8; e++) {
            float t = fmaxf(fmaf(v[e], sL[src * 128 + c0 + e],
                                 sL[src * 128 + 64 + c0 + e]), 0.f);
            av[e] = fbf(t);
        }
        #pragma unroll
        for (int nt = 0; nt < 4; nt++) {
            bf16x8 bw = ((const bf16x8*)CB)[(nt * 6 + kc) * 64 + L];
            acc[nt] = __builtin_amdgcn_mfma_f32_16x16x32_bf16(av, bw, acc[nt], 0, 0, 0);
        }
    }

    float s[4]  = {0.f, 0.f, 0.f, 0.f};
    float s2[4] = {0.f, 0.f, 0.f, 0.f};
    #pragma unroll
    for (int nt = 0; nt < 4; nt++)
        #pragma unroll
        for (int r = 0; r < 4; r++) {
            int row = R0 + quad * 4 + r;
            int col = nt * 16 + lane16;
            float v = acc[nt][r];
            out2[(size_t)row * 64 + col] = f2bf(v);
            s[nt] += v; s2[nt] += v * v;
        }
    #pragma unroll
    for (int nt = 0; nt < 4; nt++) {
        s[nt]  += __shfl_xor(s[nt], 16);
        s[nt]  += __shfl_xor(s[nt], 32);
        s2[nt] += __shfl_xor(s2[nt], 16);
        s2[nt] += __shfl_xor(s2[nt], 32);
    }
    if (quad == 0) {
        #pragma unroll
        for (int nt = 0; nt < 4; nt++) {
            red[w * 64 + nt * 16 + lane16]       = s[nt];
            red[256 + w * 64 + nt * 16 + lane16] = s2[nt];
        }
    }
    __syncthreads();
    float* myStats = stats2 + (size_t)(blockIdx.x & 7) * 128;
    if (tid < 64) {
        float t = red[tid] + red[64 + tid] + red[128 + tid] + red[192 + tid];
        atomicAdd(&myStats[tid], t);
    } else if (tid < 128) {
        int c = tid - 64;
        float t = red[256 + c] + red[320 + c] + red[384 + c] + red[448 + c];
        atomicAdd(&myStats[64 + c], t);
    }
}

// ---------------------------------------------------------------------------
// Kernel 4: final BN + ReLU + f32 store; scale2 computed in-block from the
// 8-sharded stats2. (verified R3, unchanged)
// ---------------------------------------------------------------------------
__launch_bounds__(256)
__global__ void final_pass(const bf16* __restrict__ out2, const float* __restrict__ stats2,
                           const float* __restrict__ gammas, const float* __restrict__ betas,
                           float* __restrict__ out) {
    __shared__ float sc[128];
    const int tid = threadIdx.x;
    if (tid < 64) {
        int o = tid;
        float S = 0.f, SS = 0.f;
        for (int s = 0; s < 8; s++) {
            S  += stats2[s * 128 + o];
            SS += stats2[s * 128 + 64 + o];
        }
        const float invn = 1.f / (float)BTN;
        float mu   = S * invn;
        float var  = SS * invn - mu * mu;
        float rstd = rsqrtf(var + 1e-5f);
        float a = gammas[192 + o] * rstd;
        float c = betas[192 + o] - mu * a;
        sc[o]      = a;
        sc[64 + o] = c;
    }
    __syncthreads();
    #pragma unroll
    for (int j = 0; j < 4; j++) {
        int gid = blockIdx.x * 1024 + j * 256 + tid;   // float4 index
        ushort4 u = reinterpret_cast<const ushort4*>(out2)[gid];
        const int o = (gid * 4) & 63;
        float f0, f1, f2, f3;
        unp((unsigned)u.x | ((unsigned)u.y << 16), f0, f1);
        unp((unsigned)u.z | ((unsigned)u.w << 16), f2, f3);
        float4 r;
        r.x = fmaxf(fmaf(f0, sc[o],     sc[64 + o]),     0.f);
        r.y = fmaxf(fmaf(f1, sc[o + 1], sc[64 + o + 1]), 0.f);
        r.z = fmaxf(fmaf(f2, sc[o + 2], sc[64 + o + 2]), 0.f);
        r.w = fmaxf(fmaf(f3, sc[o + 3], sc[64 + o + 3]), 0.f);
        reinterpret_cast<float4*>(out)[gid] = r;
    }
}

// ---------------------------------------------------------------------------
extern "C" void kernel_launch(void* const* d_in, const int* in_sizes, int n_in,
                              void* d_out, int out_size, void* d_ws, size_t ws_size,
                              hipStream_t stream) {
    const float* x      = (const float*)d_in[0];
    const float* W_sym  = (const float*)d_in[1];
    const float* e_sym  = (const float*)d_in[2];
    const float* W_con  = (const float*)d_in[3];
    const float* e_con  = (const float*)d_in[4];
    const float* W_dis  = (const float*)d_in[5];
    const float* att    = (const float*)d_in[6];
    const float* b_dis  = (const float*)d_in[7];
    const float* cat_w  = (const float*)d_in[8];
    const float* gammas = (const float*)d_in[9];
    const float* betas  = (const float*)d_in[10];
    const int* rows_sym = (const int*)d_in[11];
    const int* cols_sym = (const int*)d_in[12];
    const int* rows_con = (const int*)d_in[13];
    const int* cols_con = (const int*)d_in[14];
    const int nnz_s = in_sizes[2] / 64;
    const int nnz_c = in_sizes[4] / 64;

    char* p = (char*)d_ws;
    float* stats  = (float*)p; p += (size_t)STATSZ * 4;
    short* AAb    = (short*)p; p += (size_t)NN * 64 * 2 * 2;
    short* CB     = (short*)p; p += (size_t)1536 * 8 * 2;
    short* WB     = (short*)p; p += (size_t)2560 * 8 * 2;
    unsigned short* elist = (unsigned short*)p; p += 256;
    short* attF   = (short*)p; p += 128 * 16;
    bf16*  xsb    = (bf16*)p;  p += (size_t)ELEMS * 2;
    bf16*  ycb    = (bf16*)p;  p += (size_t)ELEMS * 2;
    bf16*  zb     = (bf16*)p;  p += (size_t)ELEMS * 2;
    bf16*  out2   = (bf16*)p;  p += (size_t)ELEMS * 2;
    float* stats1 = stats;
    float* stats2 = stats + NSHARD * 384;

    prep_kernel<<<19, 256, 0, stream>>>(e_sym, rows_sym, cols_sym, nnz_s,
                                        e_con, rows_con, cols_con, nnz_c,
                                        cat_w, W_sym, W_con, W_dis, att,
                                        AAb, CB, WB, elist, attF, stats);
    fused_hmix<<<BT, 256, 0, stream>>>(x, WB, AAb, attF, elist, b_dis,
                                       xsb, ycb, zb, stats1);
    mix_pass<<<1100, 256, 0, stream>>>(xsb, ycb, zb, stats1, gammas, betas,
                                       CB, out2, stats2);
    final_pass<<<1100, 256, 0, stream>>>(out2, stats2, gammas, betas, (float*)d_out);
}

// Round 8
// 172.638 us; speedup vs baseline: 2.0640x; 2.0640x over previous
//
#include <hip/hip_runtime.h>
#include <hip/hip_bf16.h>

typedef __hip_bfloat16 bf16;
typedef __attribute__((ext_vector_type(8))) short bf16x8;
typedef __attribute__((ext_vector_type(4))) float f32x4;

#define BT     3200
#define N_     22
#define NO     1408           // N_*64
#define NN     484
#define BTN    70400
#define ELEMS  4505600        // BT*N_*64
#define MAXNZ  128
#define NSHARD 16
#define STATSZ (NSHARD * 384 + 8 * 128)

static __device__ __forceinline__ bf16  f2bf(float v) { return __float2bfloat16(v); }
static __device__ __forceinline__ short fbf(float v) {
    bf16 h = __float2bfloat16(v);
    return *reinterpret_cast<short*>(&h);
}
static __device__ __forceinline__ float sbf(short s) {
    return __uint_as_float(((unsigned)(unsigned short)s) << 16);
}
static __device__ __forceinline__ void unp(unsigned u, float& lo, float& hi) {
    lo = __uint_as_float(u << 16);
    hi = __uint_as_float(u & 0xffff0000u);
}

// ---------------------------------------------------------------------------
// Kernel 1 (prep): blocks 0-1 zero own AA plane + AA softmax; 2-7 CB; 8-17 WB;
// 18: stats zero + padded edge j-lists (8/row, zero-weight sentinel) + attF.
// (verified R6 pass)
// ---------------------------------------------------------------------------
__global__ void prep_kernel(const float* __restrict__ e_s, const int* __restrict__ rs,
                            const int* __restrict__ cs, int nnz_s,
                            const float* __restrict__ e_c, const int* __restrict__ rc,
                            const int* __restrict__ cc, int nnz_c,
                            const float* __restrict__ cat_w,
                            const float* __restrict__ Wsym, const float* __restrict__ Wcon,
                            const float* __restrict__ Wdis, const float* __restrict__ att,
                            short* __restrict__ AAb, short* __restrict__ CB,
                            short* __restrict__ WB, int* __restrict__ ej,
                            short* __restrict__ attF, float* __restrict__ stats) {
    const int tid = threadIdx.x;
    if (blockIdx.x < 2) {
        __shared__ float eL[64 * (MAXNZ + 1)];
        __shared__ int rowsL[MAXNZ], colsL[MAXNZ];
        const int t = blockIdx.x;
        const float* e    = t ? e_c : e_s;
        const int*   rows = t ? rc  : rs;
        const int*   cols = t ? cc  : cs;
        const int    nnz  = t ? nnz_c : nnz_s;
        const int    str  = nnz + 1;

        // zero this block's own interleaved plane (replaces hipMemsetAsync);
        // the __syncthreads below drains stores before the scatter writes.
        for (int idx = tid; idx < NN * 64; idx += 256) AAb[(size_t)idx * 2 + t] = 0;

        for (int idx = tid; idx < 64 * nnz; idx += 256) {
            int o = idx / nnz, k = idx - o * nnz;
            eL[o * str + k] = expf(e[idx]);
        }
        for (int idx = tid; idx < nnz; idx += 256) { rowsL[idx] = rows[idx]; colsL[idx] = cols[idx]; }
        __syncthreads();

        const int o = tid & 63, ig = tid >> 6;
        float s[6];
        #pragma unroll
        for (int q = 0; q < 6; q++) s[q] = 0.f;
        for (int k = 0; k < nnz; k++) {
            int r = rowsL[k];
            float ev = eL[o * str + k];
            #pragma unroll
            for (int q = 0; q < 6; q++)
                if (r == ig + 4 * q) s[q] += ev;
        }
        float inv[6];
        #pragma unroll
        for (int q = 0; q < 6; q++) inv[q] = 1.f / s[q];
        for (int k = 0; k < nnz; k++) {
            int r = rowsL[k];
            #pragma unroll
            for (int q = 0; q < 6; q++)
                if (r == ig + 4 * q)
                    AAb[((size_t)(r * N_ + colsL[k]) * 64 + o) * 2 + t] =
                        fbf(eL[o * str + k] * inv[q]);
        }
    } else if (blockIdx.x < 8) {
        int gi = (blockIdx.x - 2) * 256 + tid;
        if (gi >= 1536) return;
        int nt = gi / 384, rem = gi % 384;
        int kc = rem >> 6, L = rem & 63;
        int n = nt * 16 + (L & 15);
        int kbase = kc * 32 + (L >> 4) * 8;
        float4 w0 = *(const float4*)&cat_w[n * 192 + kbase];
        float4 w1 = *(const float4*)&cat_w[n * 192 + kbase + 4];
        bf16x8 frag;
        frag[0] = fbf(w0.x); frag[1] = fbf(w0.y); frag[2] = fbf(w0.z); frag[3] = fbf(w0.w);
        frag[4] = fbf(w1.x); frag[5] = fbf(w1.y); frag[6] = fbf(w1.z); frag[7] = fbf(w1.w);
        ((bf16x8*)CB)[gi] = frag;
    } else if (blockIdx.x < 18) {
        int gi = (blockIdx.x - 8) * 256 + tid;
        if (gi >= 2560) return;
        int L = gi & 63;
        int q = gi >> 6;
        int nt = q & 3;
        int pk = q >> 2;
        int kc = pk & 1;
        int p  = pk >> 1;
        const float* Wsrc = (p == 0) ? Wsym :
                            (p == 1) ? Wsym + 4096 :
                            (p == 2) ? Wcon :
                            (p == 3) ? Wcon + 4096 : Wdis;
        int n  = nt * 16 + (L & 15);
        int kb = kc * 32 + (L >> 4) * 8;
        bf16x8 frag;
        #pragma unroll
        for (int j = 0; j < 8; j++) frag[j] = fbf(Wsrc[(kb + j) * 64 + n]);
        ((bf16x8*)WB)[gi] = frag;
    } else {
        // zero the atomic stats buffers (replaces hipMemsetAsync)
        for (int idx = tid; idx < STATSZ; idx += 256) stats[idx] = 0.f;
        // padded edge j-lists (off-diagonal union of sym+con), increasing-j
        // order; pad to 8 with a per-row sentinel j that is a non-edge in
        // BOTH planes (AAb there stays 0 -> fmaf adds exact 0).
        if (tid < N_) {
            unsigned bits = 0u;
            for (int e = 0; e < nnz_s; e++)
                if (rs[e] == tid && cs[e] != tid) bits |= 1u << cs[e];
            for (int e = 0; e < nnz_c; e++)
                if (rc[e] == tid && cc[e] != tid) bits |= 1u << cc[e];
            int cnt = 0;
            unsigned b = bits;
            while (b) { int j = __ffs(b) - 1; b &= b - 1; ej[tid * 8 + cnt++] = j; }
            int js = 0;
            while (((bits >> js) & 1u) || js == tid) js++;
            for (; cnt < 8; cnt++) ej[tid * 8 + cnt] = js;
        }
        // att A-fragments: A[m][k] = att[m][k] for m,k<22 else 0
        for (int f = tid; f < 128; f += 256) {
            int rt = f >> 6, LL = f & 63;
            int row = rt * 16 + (LL & 15);
            int kb  = (LL >> 4) * 8;
            bf16x8 frag;
            #pragma unroll
            for (int j = 0; j < 8; j++) {
                int k = kb + j;
                float vv = (row < N_ && k < N_) ? att[row * N_ + k] : 0.f;
                frag[j] = fbf(vv);
            }
            ((bf16x8*)attF)[f] = frag;
        }
    }
}

// ---------------------------------------------------------------------------
// Kernel 2: FUSED x-stage + h-GEMM + sparse mixer + z-MFMA. 1 bt per block,
// grid 3200. EXACT R3-verified version (172.6 µs total, 52 VGPR).
// Post-R7 note: R4 (2-bt, VGPR 116), R5 (coop fusion), R6 (ad6 hoist,
// VGPR 68), R7 (LDS FP atomics -> CAS loop, 5x slower) all regressed.
// This structure is the measured optimum; do not "improve" it without
// a counter-backed theory that predicts VGPR <= 64.
// ---------------------------------------------------------------------------
__launch_bounds__(256)
__global__ void fused_hmix(const float* __restrict__ x, const short* __restrict__ WB,
                           const short* __restrict__ AAb, const short* __restrict__ attF,
                           const int* __restrict__ ej, const float* __restrict__ bdis,
                           bf16* __restrict__ xs, bf16* __restrict__ yc,
                           bf16* __restrict__ z, float* __restrict__ stats1) {
    __shared__ __align__(16) char smem[14784];
    short*    xl   = (short*)smem;                 // [32][64] bf16, XOR-swizzled
    short*    dl   = (short*)(smem + 4096);
    float*    red4 = (float*)(smem + 8192);        // 512 f32 (dead before GEMM ends)
    unsigned* pp0  = (unsigned*)smem;              // [22][64] (after GEMM)
    unsigned* pp1  = (unsigned*)(smem + 5632);
    short*    p2   = (short*)(smem + 11264);       // [22][64]
    int*      ejL  = (int*)(smem + 14080);         // [22][8] edge lists
    float*    red  = (float*)smem;                 // stats scratch (post-mixing)

    const int g   = blockIdx.x;
    const int tid = threadIdx.x;
    const size_t base = (size_t)g * NO;
    const int w = tid >> 6, L = tid & 63;
    const int lane16 = L & 15, quad = L >> 4;
    const int colw = w * 16 + lane16;
    const bf16x8* WBf = (const bf16x8*)WB;

    // ---- (a) stage x + distance stats + edge-list stage
    if (tid < 176) ejL[tid] = ej[tid];
    float v[6], s = 0.f, s2 = 0.f;
    #pragma unroll
    for (int k = 0; k < 6; k++) {
        int i = w + 4 * k;
        float t = (i < N_) ? x[base + i * 64 + L] : 0.f;
        v[k] = t; s += t; s2 += t * t;
    }
    red4[w * 64 + L]       = s;
    red4[256 + w * 64 + L] = s2;
    for (int idx = tid; idx < 320; idx += 256) {   // zero pad rows 22..31
        ((unsigned*)xl)[704 + idx] = 0u;
        ((unsigned*)dl)[704 + idx] = 0u;
    }
    __syncthreads();
    float S  = (red4[L] + red4[64 + L]) + (red4[128 + L] + red4[192 + L]);
    float S2 = (red4[256 + L] + red4[320 + L]) + (red4[384 + L] + red4[448 + L]);
    #pragma unroll
    for (int k = 0; k < 6; k++) {
        int i = w + 4 * k;
        if (i < N_) {
            float t = v[k];
            float d2 = S2 - 2.f * t * S + (float)N_ * t * t;
            float d  = sqrtf(fmaxf(d2, 0.f)) + 1e-8f;
            int ci = i * 64 + (L ^ ((i & 7) << 3));
            xl[ci] = fbf(t);
            dl[ci] = fbf(d);
        }
    }
    __syncthreads();

    // ---- (b) GEMM: 5 planes x 2 row-tiles x 2 k-chunks
    f32x4 acc[5][2];
    #pragma unroll
    for (int p = 0; p < 5; p++)
        #pragma unroll
        for (int rt = 0; rt < 2; rt++) acc[p][rt] = (f32x4){0.f, 0.f, 0.f, 0.f};

    #pragma unroll
    for (int kc = 0; kc < 2; kc++) {
        bf16x8 ax[2], ad[2];
        #pragma unroll
        for (int rt = 0; rt < 2; rt++) {
            int row = rt * 16 + lane16;
            int ci  = row * 64 + ((kc * 32 + quad * 8) ^ ((row & 7) << 3));
            ax[rt] = *(const bf16x8*)(xl + ci);
            ad[rt] = *(const bf16x8*)(dl + ci);
        }
        #pragma unroll
        for (int p = 0; p < 5; p++) {
            bf16x8 bw = WBf[((p * 2 + kc) * 4 + w) * 64 + L];
            #pragma unroll
            for (int rt = 0; rt < 2; rt++) {
                bf16x8 a = (p < 4) ? ax[rt] : ad[rt];
                acc[p][rt] = __builtin_amdgcn_mfma_f32_16x16x32_bf16(a, bw, acc[p][rt], 0, 0, 0);
            }
        }
    }
    __syncthreads();   // xl/dl reads done before pp overwrite

    // ---- (c) epilogue pack -> LDS (high halves = h0: diag term = A[i,i]*h0)
    #pragma unroll
    for (int rt = 0; rt < 2; rt++)
        #pragma unroll
        for (int r = 0; r < 4; r++) {
            int m = rt * 16 + quad * 4 + r;
            if (m < N_) {
                float h0s = acc[0][rt][r], h1s = acc[1][rt][r];
                float h0c = acc[2][rt][r], h1c = acc[3][rt][r];
                pp0[m * 64 + colw] = (unsigned)(unsigned short)fbf(h1s) |
                                     ((unsigned)(unsigned short)fbf(h0s) << 16);
                pp1[m * 64 + colw] = (unsigned)(unsigned short)fbf(h1c) |
                                     ((unsigned)(unsigned short)fbf(h0c) << 16);
                p2[m * 64 + colw] = fbf(acc[4][rt][r]);
            }
        }
    __syncthreads();

    // ---- (d) z = att @ hdw via MFMA (K=32 pad, rows >=22 masked to 0)
    f32x4 zacc[2];
    zacc[0] = (f32x4){0.f, 0.f, 0.f, 0.f};
    zacc[1] = (f32x4){0.f, 0.f, 0.f, 0.f};
    {
        bf16x8 bfrag;
        #pragma unroll
        for (int j = 0; j < 8; j++) {
            int k = quad * 8 + j;
            bfrag[j] = (k < N_) ? p2[k * 64 + colw] : (short)0;
        }
        const bf16x8* attFf = (const bf16x8*)attF;
        #pragma unroll
        for (int rt = 0; rt < 2; rt++)
            zacc[rt] = __builtin_amdgcn_mfma_f32_16x16x32_bf16(attFf[rt * 64 + L], bfrag,
                                                               zacc[rt], 0, 0, 0);
    }

    // ---- (e) sparse sym/con mixing, fixed 8-entry padded edge lists
    float mxs[6], myc[6];
    #pragma unroll
    for (int k = 0; k < 6; k++) { mxs[k] = 0.f; myc[k] = 0.f; }
    const unsigned* AAu = (const unsigned*)AAb;
    #pragma unroll
    for (int k = 0; k < 6; k++) {
        int i = w + 4 * k;
        if (i < N_) {
            #pragma unroll
            for (int e = 0; e < 8; e++) {
                int j = ejL[i * 8 + e];
                unsigned a = AAu[(size_t)(i * N_ + j) * 64 + L];
                float as, ac; unp(a, as, ac);
                mxs[k] = fmaf(as, sbf((short)pp0[j * 64 + L]), mxs[k]);
                myc[k] = fmaf(ac, sbf((short)pp1[j * 64 + L]), myc[k]);
            }
        }
    }

    // ---- outputs + stats: xs/yc (channel = L); diag term = A[i,i]*h0[i]
    float st0 = 0.f, st1 = 0.f, st2 = 0.f, st3 = 0.f;
    #pragma unroll
    for (int k = 0; k < 6; k++) {
        int i = w + 4 * k;
        if (i < N_) {
            unsigned ad2 = AAu[(size_t)(i * 23) * 64 + L];
            float asd, acd; unp(ad2, asd, acd);
            float h0sv = __uint_as_float(pp0[i * 64 + L] & 0xffff0000u);
            float h0cv = __uint_as_float(pp1[i * 64 + L] & 0xffff0000u);
            float xsv = mxs[k] + asd * h0sv;
            float ycv = myc[k] + acd * h0cv;
            size_t oi = base + i * 64 + L;
            xs[oi] = f2bf(xsv); yc[oi] = f2bf(ycv);
            st0 += xsv; st1 += xsv * xsv;
            st2 += ycv; st3 += ycv * ycv;
        }
    }

    // z outputs + stats (channel = colw)
    float bd = bdis[colw];
    float st4 = 0.f, st5 = 0.f;
    #pragma unroll
    for (int rt = 0; rt < 2; rt++)
        #pragma unroll
        for (int r = 0; r < 4; r++) {
            int m = rt * 16 + quad * 4 + r;
            if (m < N_) {
                float zv = zacc[rt][r] + bd;
                z[base + (size_t)m * 64 + colw] = f2bf(zv);
                st4 += zv; st5 += zv * zv;
            }
        }
    st4 += __shfl_xor(st4, 16); st4 += __shfl_xor(st4, 32);
    st5 += __shfl_xor(st5, 16); st5 += __shfl_xor(st5, 32);

    __syncthreads();               // all pp/p2 reads done; reuse as red
    red[(w * 4 + 0) * 64 + L] = st0;
    red[(w * 4 + 1) * 64 + L] = st1;
    red[(w * 4 + 2) * 64 + L] = st2;
    red[(w * 4 + 3) * 64 + L] = st3;
    if (quad == 0) { red[16 * 64 + colw] = st4; red[17 * 64 + colw] = st5; }
    __syncthreads();
    float* myStats = stats1 + (size_t)(g & (NSHARD - 1)) * 384;
    for (int qq = tid; qq < 384; qq += 256) {
        int q = qq >> 6, o = qq & 63;
        float vv;
        if (q < 4)
            vv = (red[q * 64 + o] + red[(4 + q) * 64 + o]) +
                 (red[(8 + q) * 64 + o] + red[(12 + q) * 64 + o]);
        else
            vv = red[(12 + q) * 64 + o];   // q=4 -> row16, q=5 -> row17
        atomicAdd(&myStats[qq], vv);
    }
}

// ---------------------------------------------------------------------------
// Kernel 3: mix GEMM, 1100 blocks x 64 rows; scale1 computed in-block from
// stats1; stats2 sharded 8-way. (verified R3, unchanged)
// ---------------------------------------------------------------------------
__launch_bounds__(256)
__global__ void mix_pass(const bf16* __restrict__ xs, const bf16* __restrict__ yc,
                         const bf16* __restrict__ z, const float* __restrict__ stats1,
                         const float* __restrict__ gammas, const float* __restrict__ betas,
                         const short* __restrict__ CB,
                         bf16* __restrict__ out2, float* __restrict__ stats2) {
    __shared__ float sL[384];
    __shared__ float red[512];

    const int tid = threadIdx.x;
    const int w = tid >> 6, L = tid & 63;
    const int lane16 = L & 15, quad = L >> 4;
    const int R0 = blockIdx.x * 64 + w * 16;

    if (tid < 192) {
        int t = tid >> 6, o = tid & 63;
        float S = 0.f, SS = 0.f;
        for (int s = 0; s < NSHARD; s++) {
            S  += stats1[s * 384 + (2 * t) * 64 + o];
            SS += stats1[s * 384 + (2 * t + 1) * 64 + o];
        }
        const float invn = 1.f / (float)BTN;
        float mu   = S * invn;
        float var  = SS * invn - mu * mu;
        float rstd = rsqrtf(var + 1e-5f);
        float a = gammas[t * 64 + o] * rstd;
        float c = betas[t * 64 + o] - mu * a;
        sL[t * 128 + o]      = a;
        sL[t * 128 + 64 + o] = c;
    }
    __syncthreads();

    const bf16* srcs[3] = { xs, yc, z };

    f32x4 acc[4];
    #pragma unroll
    for (int nt = 0; nt < 4; nt++) acc[nt] = (f32x4){0.f, 0.f, 0.f, 0.f};

    #pragma unroll
    for (int kc = 0; kc < 6; kc++) {
        const int src = kc >> 1;
        const int c0  = (kc & 1) * 32 + quad * 8;
        int row = R0 + lane16;
        uint4 u = *(const uint4*)(srcs[src] + (size_t)row * 64 + c0);
        float v[8];
        unp(u.x, v[0], v[1]); unp(u.y, v[2], v[3]);
        unp(u.z, v[4], v[5]); unp(u.w, v[6], v[7]);
        bf16x8 av;
        #pragma unroll
        for (int e = 0; e < 8; e++) {
            float t = fmaxf(fmaf(v[e], sL[src * 128 + c0 + e],
                                 sL[src * 128 + 64 + c0 + e]), 0.f);
            av[e] = fbf(t);
        }
        #pragma unroll
        for (int nt = 0; nt < 4; nt++) {
            bf16x8 bw = ((const bf16x8*)CB)[(nt * 6 + kc) * 64 + L];
            acc[nt] = __builtin_amdgcn_mfma_f32_16x16x32_bf16(av, bw, acc[nt], 0, 0, 0);
        }
    }

    float s[4]  = {0.f, 0.f, 0.f, 0.f};
    float s2[4] = {0.f, 0.f, 0.f, 0.f};
    #pragma unroll
    for (int nt = 0; nt < 4; nt++)
        #pragma unroll
        for (int r = 0; r < 4; r++) {
            int row = R0 + quad * 4 + r;
            int col = nt * 16 + lane16;
            float v = acc[nt][r];
            out2[(size_t)row * 64 + col] = f2bf(v);
            s[nt] += v; s2[nt] += v * v;
        }
    #pragma unroll
    for (int nt = 0; nt < 4; nt++) {
        s[nt]  += __shfl_xor(s[nt], 16);
        s[nt]  += __shfl_xor(s[nt], 32);
        s2[nt] += __shfl_xor(s2[nt], 16);
        s2[nt] += __shfl_xor(s2[nt], 32);
    }
    if (quad == 0) {
        #pragma unroll
        for (int nt = 0; nt < 4; nt++) {
            red[w * 64 + nt * 16 + lane16]       = s[nt];
            red[256 + w * 64 + nt * 16 + lane16] = s2[nt];
        }
    }
    __syncthreads();
    float* myStats = stats2 + (size_t)(blockIdx.x & 7) * 128;
    if (tid < 64) {
        float t = red[tid] + red[64 + tid] + red[128 + tid] + red[192 + tid];
        atomicAdd(&myStats[tid], t);
    } else if (tid < 128) {
        int c = tid - 64;
        float t = red[256 + c] + red[320 + c] + red[384 + c] + red[448 + c];
        atomicAdd(&myStats[64 + c], t);
    }
}

// ---------------------------------------------------------------------------
// Kernel 4: final BN + ReLU + f32 store; scale2 computed in-block from the
// 8-sharded stats2. (verified R3, unchanged)
// ---------------------------------------------------------------------------
__launch_bounds__(256)
__global__ void final_pass(const bf16* __restrict__ out2, const float* __restrict__ stats2,
                           const float* __restrict__ gammas, const float* __restrict__ betas,
                           float* __restrict__ out) {
    __shared__ float sc[128];
    const int tid = threadIdx.x;
    if (tid < 64) {
        int o = tid;
        float S = 0.f, SS = 0.f;
        for (int s = 0; s < 8; s++) {
            S  += stats2[s * 128 + o];
            SS += stats2[s * 128 + 64 + o];
        }
        const float invn = 1.f / (float)BTN;
        float mu   = S * invn;
        float var  = SS * invn - mu * mu;
        float rstd = rsqrtf(var + 1e-5f);
        float a = gammas[192 + o] * rstd;
        float c = betas[192 + o] - mu * a;
        sc[o]      = a;
        sc[64 + o] = c;
    }
    __syncthreads();
    #pragma unroll
    for (int j = 0; j < 4; j++) {
        int gid = blockIdx.x * 1024 + j * 256 + tid;   // float4 index
        ushort4 u = reinterpret_cast<const ushort4*>(out2)[gid];
        const int o = (gid * 4) & 63;
        float f0, f1, f2, f3;
        unp((unsigned)u.x | ((unsigned)u.y << 16), f0, f1);
        unp((unsigned)u.z | ((unsigned)u.w << 16), f2, f3);
        float4 r;
        r.x = fmaxf(fmaf(f0, sc[o],     sc[64 + o]),     0.f);
        r.y = fmaxf(fmaf(f1, sc[o + 1], sc[64 + o + 1]), 0.f);
        r.z = fmaxf(fmaf(f2, sc[o + 2], sc[64 + o + 2]), 0.f);
        r.w = fmaxf(fmaf(f3, sc[o + 3], sc[64 + o + 3]), 0.f);
        reinterpret_cast<float4*>(out)[gid] = r;
    }
}

// ---------------------------------------------------------------------------
extern "C" void kernel_launch(void* const* d_in, const int* in_sizes, int n_in,
                              void* d_out, int out_size, void* d_ws, size_t ws_size,
                              hipStream_t stream) {
    const float* x      = (const float*)d_in[0];
    const float* W_sym  = (const float*)d_in[1];
    const float* e_sym  = (const float*)d_in[2];
    const float* W_con  = (const float*)d_in[3];
    const float* e_con  = (const float*)d_in[4];
    const float* W_dis  = (const float*)d_in[5];
    const float* att    = (const float*)d_in[6];
    const float* b_dis  = (const float*)d_in[7];
    const float* cat_w  = (const float*)d_in[8];
    const float* gammas = (const float*)d_in[9];
    const float* betas  = (const float*)d_in[10];
    const int* rows_sym = (const int*)d_in[11];
    const int* cols_sym = (const int*)d_in[12];
    const int* rows_con = (const int*)d_in[13];
    const int* cols_con = (const int*)d_in[14];
    const int nnz_s = in_sizes[2] / 64;
    const int nnz_c = in_sizes[4] / 64;

    char* p = (char*)d_ws;
    float* stats  = (float*)p; p += (size_t)STATSZ * 4;
    short* AAb    = (short*)p; p += (size_t)NN * 64 * 2 * 2;
    short* CB     = (short*)p; p += (size_t)1536 * 8 * 2;
    short* WB     = (short*)p; p += (size_t)2560 * 8 * 2;
    int*   ej     = (int*)p;   p += 192 * 4;
    short* attF   = (short*)p; p += 128 * 16;
    bf16*  xsb    = (bf16*)p;  p += (size_t)ELEMS * 2;
    bf16*  ycb    = (bf16*)p;  p += (size_t)ELEMS * 2;
    bf16*  zb     = (bf16*)p;  p += (size_t)ELEMS * 2;
    bf16*  out2   = (bf16*)p;  p += (size_t)ELEMS * 2;
    float* stats1 = stats;
    float* stats2 = stats + NSHARD * 384;

    prep_kernel<<<19, 256, 0, stream>>>(e_sym, rows_sym, cols_sym, nnz_s,
                                        e_con, rows_con, cols_con, nnz_c,
                                        cat_w, W_sym, W_con, W_dis, att,
                                        AAb, CB, WB, ej, attF, stats);
    fused_hmix<<<BT, 256, 0, stream>>>(x, WB, AAb, attF, ej, b_dis,
                                       xsb, ycb, zb, stats1);
    mix_pass<<<1100, 256, 0, stream>>>(xsb, ycb, zb, stats1, gammas, betas,
                                       CB, out2, stats2);
    final_pass<<<1100, 256, 0, stream>>>(out2, stats2, gammas, betas, (float*)d_out);
}

// Round 9
// 170.968 us; speedup vs baseline: 2.0842x; 1.0098x over previous
//
#include <hip/hip_runtime.h>
#include <hip/hip_bf16.h>

typedef __hip_bfloat16 bf16;
typedef __attribute__((ext_vector_type(8))) short bf16x8;
typedef __attribute__((ext_vector_type(4))) float f32x4;

#define BT     3200
#define N_     22
#define NO     1408           // N_*64
#define NN     484
#define BTN    70400
#define ELEMS  4505600        // BT*N_*64
#define MAXNZ  128
#define NSHARD 16
#define STATSZ (NSHARD * 384 + 8 * 128)

static __device__ __forceinline__ bf16  f2bf(float v) { return __float2bfloat16(v); }
static __device__ __forceinline__ short fbf(float v) {
    bf16 h = __float2bfloat16(v);
    return *reinterpret_cast<short*>(&h);
}
static __device__ __forceinline__ float sbf(short s) {
    return __uint_as_float(((unsigned)(unsigned short)s) << 16);
}
static __device__ __forceinline__ void unp(unsigned u, float& lo, float& hi) {
    lo = __uint_as_float(u << 16);
    hi = __uint_as_float(u & 0xffff0000u);
}

// ---------------------------------------------------------------------------
// Kernel 1 (prep): blocks 0-1 zero own AA plane + AA softmax; 2-7 CB; 8-17 WB;
// 18: stats zero + padded edge j-lists (8/row, zero-weight sentinel) + attF.
// (verified R6/R8)
// ---------------------------------------------------------------------------
__global__ void prep_kernel(const float* __restrict__ e_s, const int* __restrict__ rs,
                            const int* __restrict__ cs, int nnz_s,
                            const float* __restrict__ e_c, const int* __restrict__ rc,
                            const int* __restrict__ cc, int nnz_c,
                            const float* __restrict__ cat_w,
                            const float* __restrict__ Wsym, const float* __restrict__ Wcon,
                            const float* __restrict__ Wdis, const float* __restrict__ att,
                            short* __restrict__ AAb, short* __restrict__ CB,
                            short* __restrict__ WB, int* __restrict__ ej,
                            short* __restrict__ attF, float* __restrict__ stats) {
    const int tid = threadIdx.x;
    if (blockIdx.x < 2) {
        __shared__ float eL[64 * (MAXNZ + 1)];
        __shared__ int rowsL[MAXNZ], colsL[MAXNZ];
        const int t = blockIdx.x;
        const float* e    = t ? e_c : e_s;
        const int*   rows = t ? rc  : rs;
        const int*   cols = t ? cc  : cs;
        const int    nnz  = t ? nnz_c : nnz_s;
        const int    str  = nnz + 1;

        // zero this block's own interleaved plane (replaces hipMemsetAsync);
        // the __syncthreads below drains stores before the scatter writes.
        for (int idx = tid; idx < NN * 64; idx += 256) AAb[(size_t)idx * 2 + t] = 0;

        for (int idx = tid; idx < 64 * nnz; idx += 256) {
            int o = idx / nnz, k = idx - o * nnz;
            eL[o * str + k] = expf(e[idx]);
        }
        for (int idx = tid; idx < nnz; idx += 256) { rowsL[idx] = rows[idx]; colsL[idx] = cols[idx]; }
        __syncthreads();

        const int o = tid & 63, ig = tid >> 6;
        float s[6];
        #pragma unroll
        for (int q = 0; q < 6; q++) s[q] = 0.f;
        for (int k = 0; k < nnz; k++) {
            int r = rowsL[k];
            float ev = eL[o * str + k];
            #pragma unroll
            for (int q = 0; q < 6; q++)
                if (r == ig + 4 * q) s[q] += ev;
        }
        float inv[6];
        #pragma unroll
        for (int q = 0; q < 6; q++) inv[q] = 1.f / s[q];
        for (int k = 0; k < nnz; k++) {
            int r = rowsL[k];
            #pragma unroll
            for (int q = 0; q < 6; q++)
                if (r == ig + 4 * q)
                    AAb[((size_t)(r * N_ + colsL[k]) * 64 + o) * 2 + t] =
                        fbf(eL[o * str + k] * inv[q]);
        }
    } else if (blockIdx.x < 8) {
        int gi = (blockIdx.x - 2) * 256 + tid;
        if (gi >= 1536) return;
        int nt = gi / 384, rem = gi % 384;
        int kc = rem >> 6, L = rem & 63;
        int n = nt * 16 + (L & 15);
        int kbase = kc * 32 + (L >> 4) * 8;
        float4 w0 = *(const float4*)&cat_w[n * 192 + kbase];
        float4 w1 = *(const float4*)&cat_w[n * 192 + kbase + 4];
        bf16x8 frag;
        frag[0] = fbf(w0.x); frag[1] = fbf(w0.y); frag[2] = fbf(w0.z); frag[3] = fbf(w0.w);
        frag[4] = fbf(w1.x); frag[5] = fbf(w1.y); frag[6] = fbf(w1.z); frag[7] = fbf(w1.w);
        ((bf16x8*)CB)[gi] = frag;
    } else if (blockIdx.x < 18) {
        int gi = (blockIdx.x - 8) * 256 + tid;
        if (gi >= 2560) return;
        int L = gi & 63;
        int q = gi >> 6;
        int nt = q & 3;
        int pk = q >> 2;
        int kc = pk & 1;
        int p  = pk >> 1;
        const float* Wsrc = (p == 0) ? Wsym :
                            (p == 1) ? Wsym + 4096 :
                            (p == 2) ? Wcon :
                            (p == 3) ? Wcon + 4096 : Wdis;
        int n  = nt * 16 + (L & 15);
        int kb = kc * 32 + (L >> 4) * 8;
        bf16x8 frag;
        #pragma unroll
        for (int j = 0; j < 8; j++) frag[j] = fbf(Wsrc[(kb + j) * 64 + n]);
        ((bf16x8*)WB)[gi] = frag;
    } else {
        // zero the atomic stats buffers (replaces hipMemsetAsync)
        for (int idx = tid; idx < STATSZ; idx += 256) stats[idx] = 0.f;
        // padded edge j-lists (off-diagonal union of sym+con), increasing-j
        // order; pad to 8 with a per-row sentinel j that is a non-edge in
        // BOTH planes (AAb there stays 0 -> fmaf adds exact 0).
        if (tid < N_) {
            unsigned bits = 0u;
            for (int e = 0; e < nnz_s; e++)
                if (rs[e] == tid && cs[e] != tid) bits |= 1u << cs[e];
            for (int e = 0; e < nnz_c; e++)
                if (rc[e] == tid && cc[e] != tid) bits |= 1u << cc[e];
            int cnt = 0;
            unsigned b = bits;
            while (b) { int j = __ffs(b) - 1; b &= b - 1; ej[tid * 8 + cnt++] = j; }
            int js = 0;
            while (((bits >> js) & 1u) || js == tid) js++;
            for (; cnt < 8; cnt++) ej[tid * 8 + cnt] = js;
        }
        // att A-fragments: A[m][k] = att[m][k] for m,k<22 else 0
        for (int f = tid; f < 128; f += 256) {
            int rt = f >> 6, LL = f & 63;
            int row = rt * 16 + (LL & 15);
            int kb  = (LL >> 4) * 8;
            bf16x8 frag;
            #pragma unroll
            for (int j = 0; j < 8; j++) {
                int k = kb + j;
                float vv = (row < N_ && k < N_) ? att[row * N_ + k] : 0.f;
                frag[j] = fbf(vv);
            }
            ((bf16x8*)attF)[f] = frag;
        }
    }
}

// ---------------------------------------------------------------------------
// Kernel 2: FUSED x-stage + h-GEMM + sparse mixer + z-MFMA. 1 bt per block,
// grid 3200. EXACT R3/R8-verified version (172.6 µs total, 52 VGPR).
// Post-R7 note: R4 (2-bt, VGPR 116), R5 (coop fusion), R6 (ad6 hoist,
// VGPR 68), R7 (LDS FP atomics -> CAS loop, 5x slower) all regressed.
// This structure is the measured optimum; do not "improve" it without
// a counter-backed theory that predicts VGPR <= 64.
// ---------------------------------------------------------------------------
__launch_bounds__(256)
__global__ void fused_hmix(const float* __restrict__ x, const short* __restrict__ WB,
                           const short* __restrict__ AAb, const short* __restrict__ attF,
                           const int* __restrict__ ej, const float* __restrict__ bdis,
                           bf16* __restrict__ xs, bf16* __restrict__ yc,
                           bf16* __restrict__ z, float* __restrict__ stats1) {
    __shared__ __align__(16) char smem[14784];
    short*    xl   = (short*)smem;                 // [32][64] bf16, XOR-swizzled
    short*    dl   = (short*)(smem + 4096);
    float*    red4 = (float*)(smem + 8192);        // 512 f32 (dead before GEMM ends)
    unsigned* pp0  = (unsigned*)smem;              // [22][64] (after GEMM)
    unsigned* pp1  = (unsigned*)(smem + 5632);
    short*    p2   = (short*)(smem + 11264);       // [22][64]
    int*      ejL  = (int*)(smem + 14080);         // [22][8] edge lists
    float*    red  = (float*)smem;                 // stats scratch (post-mixing)

    const int g   = blockIdx.x;
    const int tid = threadIdx.x;
    const size_t base = (size_t)g * NO;
    const int w = tid >> 6, L = tid & 63;
    const int lane16 = L & 15, quad = L >> 4;
    const int colw = w * 16 + lane16;
    const bf16x8* WBf = (const bf16x8*)WB;

    // ---- (a) stage x + distance stats + edge-list stage
    if (tid < 176) ejL[tid] = ej[tid];
    float v[6], s = 0.f, s2 = 0.f;
    #pragma unroll
    for (int k = 0; k < 6; k++) {
        int i = w + 4 * k;
        float t = (i < N_) ? x[base + i * 64 + L] : 0.f;
        v[k] = t; s += t; s2 += t * t;
    }
    red4[w * 64 + L]       = s;
    red4[256 + w * 64 + L] = s2;
    for (int idx = tid; idx < 320; idx += 256) {   // zero pad rows 22..31
        ((unsigned*)xl)[704 + idx] = 0u;
        ((unsigned*)dl)[704 + idx] = 0u;
    }
    __syncthreads();
    float S  = (red4[L] + red4[64 + L]) + (red4[128 + L] + red4[192 + L]);
    float S2 = (red4[256 + L] + red4[320 + L]) + (red4[384 + L] + red4[448 + L]);
    #pragma unroll
    for (int k = 0; k < 6; k++) {
        int i = w + 4 * k;
        if (i < N_) {
            float t = v[k];
            float d2 = S2 - 2.f * t * S + (float)N_ * t * t;
            float d  = sqrtf(fmaxf(d2, 0.f)) + 1e-8f;
            int ci = i * 64 + (L ^ ((i & 7) << 3));
            xl[ci] = fbf(t);
            dl[ci] = fbf(d);
        }
    }
    __syncthreads();

    // ---- (b) GEMM: 5 planes x 2 row-tiles x 2 k-chunks
    f32x4 acc[5][2];
    #pragma unroll
    for (int p = 0; p < 5; p++)
        #pragma unroll
        for (int rt = 0; rt < 2; rt++) acc[p][rt] = (f32x4){0.f, 0.f, 0.f, 0.f};

    #pragma unroll
    for (int kc = 0; kc < 2; kc++) {
        bf16x8 ax[2], ad[2];
        #pragma unroll
        for (int rt = 0; rt < 2; rt++) {
            int row = rt * 16 + lane16;
            int ci  = row * 64 + ((kc * 32 + quad * 8) ^ ((row & 7) << 3));
            ax[rt] = *(const bf16x8*)(xl + ci);
            ad[rt] = *(const bf16x8*)(dl + ci);
        }
        #pragma unroll
        for (int p = 0; p < 5; p++) {
            bf16x8 bw = WBf[((p * 2 + kc) * 4 + w) * 64 + L];
            #pragma unroll
            for (int rt = 0; rt < 2; rt++) {
                bf16x8 a = (p < 4) ? ax[rt] : ad[rt];
                acc[p][rt] = __builtin_amdgcn_mfma_f32_16x16x32_bf16(a, bw, acc[p][rt], 0, 0, 0);
            }
        }
    }
    __syncthreads();   // xl/dl reads done before pp overwrite

    // ---- (c) epilogue pack -> LDS (high halves = h0: diag term = A[i,i]*h0)
    #pragma unroll
    for (int rt = 0; rt < 2; rt++)
        #pragma unroll
        for (int r = 0; r < 4; r++) {
            int m = rt * 16 + quad * 4 + r;
            if (m < N_) {
                float h0s = acc[0][rt][r], h1s = acc[1][rt][r];
                float h0c = acc[2][rt][r], h1c = acc[3][rt][r];
                pp0[m * 64 + colw] = (unsigned)(unsigned short)fbf(h1s) |
                                     ((unsigned)(unsigned short)fbf(h0s) << 16);
                pp1[m * 64 + colw] = (unsigned)(unsigned short)fbf(h1c) |
                                     ((unsigned)(unsigned short)fbf(h0c) << 16);
                p2[m * 64 + colw] = fbf(acc[4][rt][r]);
            }
        }
    __syncthreads();

    // ---- (d) z = att @ hdw via MFMA (K=32 pad, rows >=22 masked to 0)
    f32x4 zacc[2];
    zacc[0] = (f32x4){0.f, 0.f, 0.f, 0.f};
    zacc[1] = (f32x4){0.f, 0.f, 0.f, 0.f};
    {
        bf16x8 bfrag;
        #pragma unroll
        for (int j = 0; j < 8; j++) {
            int k = quad * 8 + j;
            bfrag[j] = (k < N_) ? p2[k * 64 + colw] : (short)0;
        }
        const bf16x8* attFf = (const bf16x8*)attF;
        #pragma unroll
        for (int rt = 0; rt < 2; rt++)
            zacc[rt] = __builtin_amdgcn_mfma_f32_16x16x32_bf16(attFf[rt * 64 + L], bfrag,
                                                               zacc[rt], 0, 0, 0);
    }

    // ---- (e) sparse sym/con mixing, fixed 8-entry padded edge lists
    float mxs[6], myc[6];
    #pragma unroll
    for (int k = 0; k < 6; k++) { mxs[k] = 0.f; myc[k] = 0.f; }
    const unsigned* AAu = (const unsigned*)AAb;
    #pragma unroll
    for (int k = 0; k < 6; k++) {
        int i = w + 4 * k;
        if (i < N_) {
            #pragma unroll
            for (int e = 0; e < 8; e++) {
                int j = ejL[i * 8 + e];
                unsigned a = AAu[(size_t)(i * N_ + j) * 64 + L];
                float as, ac; unp(a, as, ac);
                mxs[k] = fmaf(as, sbf((short)pp0[j * 64 + L]), mxs[k]);
                myc[k] = fmaf(ac, sbf((short)pp1[j * 64 + L]), myc[k]);
            }
        }
    }

    // ---- outputs + stats: xs/yc (channel = L); diag term = A[i,i]*h0[i]
    float st0 = 0.f, st1 = 0.f, st2 = 0.f, st3 = 0.f;
    #pragma unroll
    for (int k = 0; k < 6; k++) {
        int i = w + 4 * k;
        if (i < N_) {
            unsigned ad2 = AAu[(size_t)(i * 23) * 64 + L];
            float asd, acd; unp(ad2, asd, acd);
            float h0sv = __uint_as_float(pp0[i * 64 + L] & 0xffff0000u);
            float h0cv = __uint_as_float(pp1[i * 64 + L] & 0xffff0000u);
            float xsv = mxs[k] + asd * h0sv;
            float ycv = myc[k] + acd * h0cv;
            size_t oi = base + i * 64 + L;
            xs[oi] = f2bf(xsv); yc[oi] = f2bf(ycv);
            st0 += xsv; st1 += xsv * xsv;
            st2 += ycv; st3 += ycv * ycv;
        }
    }

    // z outputs + stats (channel = colw)
    float bd = bdis[colw];
    float st4 = 0.f, st5 = 0.f;
    #pragma unroll
    for (int rt = 0; rt < 2; rt++)
        #pragma unroll
        for (int r = 0; r < 4; r++) {
            int m = rt * 16 + quad * 4 + r;
            if (m < N_) {
                float zv = zacc[rt][r] + bd;
                z[base + (size_t)m * 64 + colw] = f2bf(zv);
                st4 += zv; st5 += zv * zv;
            }
        }
    st4 += __shfl_xor(st4, 16); st4 += __shfl_xor(st4, 32);
    st5 += __shfl_xor(st5, 16); st5 += __shfl_xor(st5, 32);

    __syncthreads();               // all pp/p2 reads done; reuse as red
    red[(w * 4 + 0) * 64 + L] = st0;
    red[(w * 4 + 1) * 64 + L] = st1;
    red[(w * 4 + 2) * 64 + L] = st2;
    red[(w * 4 + 3) * 64 + L] = st3;
    if (quad == 0) { red[16 * 64 + colw] = st4; red[17 * 64 + colw] = st5; }
    __syncthreads();
    float* myStats = stats1 + (size_t)(g & (NSHARD - 1)) * 384;
    for (int qq = tid; qq < 384; qq += 256) {
        int q = qq >> 6, o = qq & 63;
        float vv;
        if (q < 4)
            vv = (red[q * 64 + o] + red[(4 + q) * 64 + o]) +
                 (red[(8 + q) * 64 + o] + red[(12 + q) * 64 + o]);
        else
            vv = red[(12 + q) * 64 + o];   // q=4 -> row16, q=5 -> row17
        atomicAdd(&myStats[qq], vv);
    }
}

// ---------------------------------------------------------------------------
// Kernel 3: mix GEMM, 1100 blocks x 64 rows. R9 change: all 6 source uint4
// loads hoisted to the TOP of the kernel (before sL staging + barrier) so
// they issue in one latency shadow and overlap the 16-shard stats reduce.
// Identical arithmetic/addresses -> bit-identical output.
// ---------------------------------------------------------------------------
__launch_bounds__(256)
__global__ void mix_pass(const bf16* __restrict__ xs, const bf16* __restrict__ yc,
                         const bf16* __restrict__ z, const float* __restrict__ stats1,
                         const float* __restrict__ gammas, const float* __restrict__ betas,
                         const short* __restrict__ CB,
                         bf16* __restrict__ out2, float* __restrict__ stats2) {
    __shared__ float sL[384];
    __shared__ float red[512];

    const int tid = threadIdx.x;
    const int w = tid >> 6, L = tid & 63;
    const int lane16 = L & 15, quad = L >> 4;
    const int R0 = blockIdx.x * 64 + w * 16;

    // ---- prefetch all 6 source chunks (independent; one latency shadow)
    const bf16* srcs[3] = { xs, yc, z };
    uint4 u6[6];
    #pragma unroll
    for (int kc = 0; kc < 6; kc++) {
        const int src = kc >> 1;
        const int c0  = (kc & 1) * 32 + quad * 8;
        int row = R0 + lane16;
        u6[kc] = *(const uint4*)(srcs[src] + (size_t)row * 64 + c0);
    }

    // ---- scale1 from 16-sharded stats1 (overlaps the u6 loads)
    if (tid < 192) {
        int t = tid >> 6, o = tid & 63;
        float S = 0.f, SS = 0.f;
        for (int s = 0; s < NSHARD; s++) {
            S  += stats1[s * 384 + (2 * t) * 64 + o];
            SS += stats1[s * 384 + (2 * t + 1) * 64 + o];
        }
        const float invn = 1.f / (float)BTN;
        float mu   = S * invn;
        float var  = SS * invn - mu * mu;
        float rstd = rsqrtf(var + 1e-5f);
        float a = gammas[t * 64 + o] * rstd;
        float c = betas[t * 64 + o] - mu * a;
        sL[t * 128 + o]      = a;
        sL[t * 128 + 64 + o] = c;
    }
    __syncthreads();

    f32x4 acc[4];
    #pragma unroll
    for (int nt = 0; nt < 4; nt++) acc[nt] = (f32x4){0.f, 0.f, 0.f, 0.f};

    #pragma unroll
    for (int kc = 0; kc < 6; kc++) {
        const int src = kc >> 1;
        const int c0  = (kc & 1) * 32 + quad * 8;
        float v[8];
        unp(u6[kc].x, v[0], v[1]); unp(u6[kc].y, v[2], v[3]);
        unp(u6[kc].z, v[4], v[5]); unp(u6[kc].w, v[6], v[7]);
        bf16x8 av;
        #pragma unroll
        for (int e = 0; e < 8; e++) {
            float t = fmaxf(fmaf(v[e], sL[src * 128 + c0 + e],
                                 sL[src * 128 + 64 + c0 + e]), 0.f);
            av[e] = fbf(t);
        }
        #pragma unroll
        for (int nt = 0; nt < 4; nt++) {
            bf16x8 bw = ((const bf16x8*)CB)[(nt * 6 + kc) * 64 + L];
            acc[nt] = __builtin_amdgcn_mfma_f32_16x16x32_bf16(av, bw, acc[nt], 0, 0, 0);
        }
    }

    float s[4]  = {0.f, 0.f, 0.f, 0.f};
    float s2[4] = {0.f, 0.f, 0.f, 0.f};
    #pragma unroll
    for (int nt = 0; nt < 4; nt++)
        #pragma unroll
        for (int r = 0; r < 4; r++) {
            int row = R0 + quad * 4 + r;
            int col = nt * 16 + lane16;
            float v = acc[nt][r];
            out2[(size_t)row * 64 + col] = f2bf(v);
            s[nt] += v; s2[nt] += v * v;
        }
    #pragma unroll
    for (int nt = 0; nt < 4; nt++) {
        s[nt]  += __shfl_xor(s[nt], 16);
        s[nt]  += __shfl_xor(s[nt], 32);
        s2[nt] += __shfl_xor(s2[nt], 16);
        s2[nt] += __shfl_xor(s2[nt], 32);
    }
    if (quad == 0) {
        #pragma unroll
        for (int nt = 0; nt < 4; nt++) {
            red[w * 64 + nt * 16 + lane16]       = s[nt];
            red[256 + w * 64 + nt * 16 + lane16] = s2[nt];
        }
    }
    __syncthreads();
    float* myStats = stats2 + (size_t)(blockIdx.x & 7) * 128;
    if (tid < 64) {
        float t = red[tid] + red[64 + tid] + red[128 + tid] + red[192 + tid];
        atomicAdd(&myStats[tid], t);
    } else if (tid < 128) {
        int c = tid - 64;
        float t = red[256 + c] + red[320 + c] + red[384 + c] + red[448 + c];
        atomicAdd(&myStats[64 + c], t);
    }
}

// ---------------------------------------------------------------------------
// Kernel 4: final BN + ReLU + f32 store; scale2 computed in-block from the
// 8-sharded stats2. (verified R3/R8, unchanged)
// ---------------------------------------------------------------------------
__launch_bounds__(256)
__global__ void final_pass(const bf16* __restrict__ out2, const float* __restrict__ stats2,
                           const float* __restrict__ gammas, const float* __restrict__ betas,
                           float* __restrict__ out) {
    __shared__ float sc[128];
    const int tid = threadIdx.x;
    if (tid < 64) {
        int o = tid;
        float S = 0.f, SS = 0.f;
        for (int s = 0; s < 8; s++) {
            S  += stats2[s * 128 + o];
            SS += stats2[s * 128 + 64 + o];
        }
        const float invn = 1.f / (float)BTN;
        float mu   = S * invn;
        float var  = SS * invn - mu * mu;
        float rstd = rsqrtf(var + 1e-5f);
        float a = gammas[192 + o] * rstd;
        float c = betas[192 + o] - mu * a;
        sc[o]      = a;
        sc[64 + o] = c;
    }
    __syncthreads();
    #pragma unroll
    for (int j = 0; j < 4; j++) {
        int gid = blockIdx.x * 1024 + j * 256 + tid;   // float4 index
        ushort4 u = reinterpret_cast<const ushort4*>(out2)[gid];
        const int o = (gid * 4) & 63;
        float f0, f1, f2, f3;
        unp((unsigned)u.x | ((unsigned)u.y << 16), f0, f1);
        unp((unsigned)u.z | ((unsigned)u.w << 16), f2, f3);
        float4 r;
        r.x = fmaxf(fmaf(f0, sc[o],     sc[64 + o]),     0.f);
        r.y = fmaxf(fmaf(f1, sc[o + 1], sc[64 + o + 1]), 0.f);
        r.z = fmaxf(fmaf(f2, sc[o + 2], sc[64 + o + 2]), 0.f);
        r.w = fmaxf(fmaf(f3, sc[o + 3], sc[64 + o + 3]), 0.f);
        reinterpret_cast<float4*>(out)[gid] = r;
    }
}

// ---------------------------------------------------------------------------
extern "C" void kernel_launch(void* const* d_in, const int* in_sizes, int n_in,
                              void* d_out, int out_size, void* d_ws, size_t ws_size,
                              hipStream_t stream) {
    const float* x      = (const float*)d_in[0];
    const float* W_sym  = (const float*)d_in[1];
    const float* e_sym  = (const float*)d_in[2];
    const float* W_con  = (const float*)d_in[3];
    const float* e_con  = (const float*)d_in[4];
    const float* W_dis  = (const float*)d_in[5];
    const float* att    = (const float*)d_in[6];
    const float* b_dis  = (const float*)d_in[7];
    const float* cat_w  = (const float*)d_in[8];
    const float* gammas = (const float*)d_in[9];
    const float* betas  = (const float*)d_in[10];
    const int* rows_sym = (const int*)d_in[11];
    const int* cols_sym = (const int*)d_in[12];
    const int* rows_con = (const int*)d_in[13];
    const int* cols_con = (const int*)d_in[14];
    const int nnz_s = in_sizes[2] / 64;
    const int nnz_c = in_sizes[4] / 64;

    char* p = (char*)d_ws;
    float* stats  = (float*)p; p += (size_t)STATSZ * 4;
    short* AAb    = (short*)p; p += (size_t)NN * 64 * 2 * 2;
    short* CB     = (short*)p; p += (size_t)1536 * 8 * 2;
    short* WB     = (short*)p; p += (size_t)2560 * 8 * 2;
    int*   ej     = (int*)p;   p += 192 * 4;
    short* attF   = (short*)p; p += 128 * 16;
    bf16*  xsb    = (bf16*)p;  p += (size_t)ELEMS * 2;
    bf16*  ycb    = (bf16*)p;  p += (size_t)ELEMS * 2;
    bf16*  zb     = (bf16*)p;  p += (size_t)ELEMS * 2;
    bf16*  out2   = (bf16*)p;  p += (size_t)ELEMS * 2;
    float* stats1 = stats;
    float* stats2 = stats + NSHARD * 384;

    prep_kernel<<<19, 256, 0, stream>>>(e_sym, rows_sym, cols_sym, nnz_s,
                                        e_con, rows_con, cols_con, nnz_c,
                                        cat_w, W_sym, W_con, W_dis, att,
                                        AAb, CB, WB, ej, attF, stats);
    fused_hmix<<<BT, 256, 0, stream>>>(x, WB, AAb, attF, ej, b_dis,
                                       xsb, ycb, zb, stats1);
    mix_pass<<<1100, 256, 0, stream>>>(xsb, ycb, zb, stats1, gammas, betas,
                                       CB, out2, stats2);
    final_pass<<<1100, 256, 0, stream>>>(out2, stats2, gammas, betas, (float*)d_out);
}